// Round 5
// baseline (730.576 us; speedup 1.0000x reference)
//
#include <hip/hip_runtime.h>
#include <hip/hip_bf16.h>
#include <math.h>

#define B_ 256
#define T_ 240
#define N_ 264
#define H_ 256
#define BN_ (B_ * N_)
#define PHI_ 0.94247778f   // 3.1415926 * 0.3
#define MAXNORM_ 0.996f    // (1 - 4e-3)/sqrt(c), c=1

typedef short short8 __attribute__((ext_vector_type(8)));     // 8 bf16 (4 VGPRs) MFMA A/B frag
typedef float f32x4 __attribute__((ext_vector_type(4)));      // MFMA C/D frag
typedef unsigned short ushort4v __attribute__((ext_vector_type(4)));

__device__ inline unsigned short f2bf(float f) {
  __hip_bfloat16 h = __float2bfloat16(f);
  return *reinterpret_cast<unsigned short*>(&h);
}
__device__ inline float bf2f(unsigned short u) {
  unsigned int x = ((unsigned int)u) << 16;
  return __uint_as_float(x);
}

// Conflict-free 16B-granule LDS placement for [row][kg] staging.
// Verified: every aligned 8-lane group hits 8 distinct (mod 8) 16B slots for
// both the staging ds_write (lane->(row=l>>2,kg=l&3)) and the fragment
// ds_read (lane=(g,l4) -> (row=fr*16+l4, kg=g)).
__device__ inline int swz16(int row, int kg) {
  return row * 4 + ((kg ^ (row >> 1)) & 3);
}

// ---------------------------------------------------------------------------
// Kernel 1: fused stats + transposed normalize:
// z[b][n][t] = bf16((data[b][t][n]-mean_n)*rdev_n), t in [0,256), t>=240 -> 0
// ---------------------------------------------------------------------------
__global__ __launch_bounds__(256) void zTs_kernel(
    const float* __restrict__ data, unsigned short* __restrict__ z) {
  int b = blockIdx.y;
  int n0 = blockIdx.x * 64;
  __shared__ float ld[240 * 65];          // [t][col], stride 65 -> conflict-free both axes
  __shared__ float ps[4][64], pq[4][64];
  __shared__ float mS[64], rS[64];
  int tid = threadIdx.x, lane = tid & 63, wv = tid >> 6;
  int n = n0 + lane;
  bool nv = n < N_;
  for (int t = wv; t < T_; t += 4)
    ld[t * 65 + lane] = nv ? data[((size_t)b * T_ + t) * N_ + n] : 0.f;
  __syncthreads();
  {
    int col = tid & 63, q = tid >> 6;
    float s = 0.f, ss = 0.f;
    for (int t = q * 60; t < q * 60 + 60; ++t) { float v = ld[t * 65 + col]; s += v; ss += v * v; }
    ps[q][col] = s; pq[q][col] = ss;
  }
  __syncthreads();
  if (tid < 64) {
    float s  = ps[0][tid] + ps[1][tid] + ps[2][tid] + ps[3][tid];
    float ss = pq[0][tid] + pq[1][tid] + pq[2][tid] + pq[3][tid];
    float m = s / (float)T_;
    float var = ss - s * m;
    float d = sqrtf(fmaxf(var, 0.f));
    mS[tid] = m;
    rS[tid] = (d > 0.f) ? (1.f / d) : 0.f;   // nan_to_num semantics
  }
  __syncthreads();
  int nrows = min(64, N_ - n0);
  for (int rr = 0; rr < nrows; ++rr) {
    float m = mS[rr], r = rS[rr];
    unsigned short val = (tid < T_) ? f2bf((ld[tid * 65 + rr] - m) * r) : (unsigned short)0;
    z[((size_t)(b * N_ + n0 + rr)) * 256 + tid] = val;
  }
}

// ---------------------------------------------------------------------------
// Kernel 2: WT[h][j] = bf16(W[j][h]), j-pad to Jpad with zeros
// ---------------------------------------------------------------------------
__global__ __launch_bounds__(256) void wtrans_kernel(
    const float* __restrict__ W, unsigned short* __restrict__ WT,
    int Jv, int Jpad) {
  int jt = blockIdx.x * 64, ht = blockIdx.y * 64;
  __shared__ float tile[64][65];
  int tid = threadIdx.x;
  for (int idx = tid; idx < 4096; idx += 256) {
    int jr = idx >> 6, hr = idx & 63;
    int j = jt + jr;
    tile[jr][hr] = (j < Jv) ? W[(size_t)j * H_ + ht + hr] : 0.f;
  }
  __syncthreads();
  for (int idx = tid; idx < 4096; idx += 256) {
    int hr = idx >> 6, jr = idx & 63;
    int j = jt + jr;
    if (j < Jpad) WT[(size_t)(ht + hr) * Jpad + j] = f2bf(tile[jr][hr]);
  }
}

// ---------------------------------------------------------------------------
// MFMA GEMM template: C[64 x 256] tile per block, 4 waves, K-step 32.
// A row-major [rowsA][lda] bf16 (clamped), B^T row-major [validB][ldb] bf16
// (zero-filled past validB).
// EPI 0: corr -> adjF f32 + adjB bf16 [264][288]; row-sum partials -> dsum (atomic)
// EPI 1: aw   -> YT bf16 [256][288]: YT[h][j] = rsqrt(1+dsum_j) * acc (pad 0)
// EPI 2: lx   -> g1 bf16 [264][256], fused bias + L-diag + project/logmap/act
// EPI 3: lx   -> g2 f32  [264][256], same epilogue
// Block ids are XCD-remapped (bijective, nwg % 8 == 0 for all grids).
// ---------------------------------------------------------------------------
template<int EPI>
__global__ __launch_bounds__(256) void mfma_gemm_kernel(
    const unsigned short* __restrict__ A, int lda, long sA, int rowsA,
    const unsigned short* __restrict__ Bm, int ldb, long sB, int validB,
    int ksteps,
    float* __restrict__ outF, unsigned short* __restrict__ outB,
    float* __restrict__ dsum, const float* __restrict__ bias) {
  // XCD-aware remap: consecutive work-ids (same batch) -> same XCD chunk
  int gx = gridDim.x, gy = gridDim.y;
  int flat = (blockIdx.z * gy + blockIdx.y) * gx + blockIdx.x;
  int nwg = gx * gy * gridDim.z;
  int q8 = nwg >> 3;
  int id = (flat & 7) * q8 + (flat >> 3);
  int bx = id % gx; int tq = id / gx;
  int b = tq / gy;
  int i0 = (tq % gy) * 64;
  int n0 = bx * 256;

  int tid = threadIdx.x;
  int w = tid >> 6, lane = tid & 63, g = lane >> 4, l4 = lane & 15;

  __shared__ short8 AsV[256];    // swz16(row 0..63, kg 0..3)   : 4 KB
  __shared__ short8 BsV[1024];   // swz16(col 0..255, kg 0..3)  : 16 KB

  const unsigned short* Ab = A + (size_t)b * sA;
  const unsigned short* Bb = Bm + (size_t)b * sB;

  f32x4 acc[4][4];
#pragma unroll
  for (int x = 0; x < 4; ++x)
#pragma unroll
    for (int y = 0; y < 4; ++y) acc[x][y] = (f32x4){0.f, 0.f, 0.f, 0.f};

  int arow = tid >> 2, akg = tid & 3;        // staging coords (64B/row coalesced)
  int rA = min(i0 + arow, rowsA - 1);        // clamp (dup rows discarded in epilogue)
  const unsigned short* Aptr = Ab + (size_t)rA * lda + akg * 8;
  bool wactive = (n0 + w * 64) < validB;     // corr x=1: waves 1-3 fully invalid
  const short8 zero8 = {};

  for (int ks = 0; ks < ksteps; ++ks) {
    int k0 = ks * 32;
    short8 av = *(const short8*)(Aptr + k0);
    short8 bv[4];
#pragma unroll
    for (int it = 0; it < 4; ++it) {
      int nn = n0 + arow + it * 64;
      bv[it] = (nn < validB) ? *(const short8*)(Bb + (size_t)nn * ldb + k0 + akg * 8) : zero8;
    }
    __syncthreads();
    AsV[swz16(arow, akg)] = av;
#pragma unroll
    for (int it = 0; it < 4; ++it) BsV[swz16(arow + it * 64, akg)] = bv[it];
    __syncthreads();
    if (wactive) {
      short8 af[4], bfr[4];
#pragma unroll
      for (int fr = 0; fr < 4; ++fr) af[fr] = AsV[swz16(fr * 16 + l4, g)];
#pragma unroll
      for (int fc = 0; fc < 4; ++fc) bfr[fc] = BsV[swz16(w * 64 + fc * 16 + l4, g)];
#pragma unroll
      for (int fr = 0; fr < 4; ++fr)
#pragma unroll
        for (int fc = 0; fc < 4; ++fc)
          acc[fr][fc] = __builtin_amdgcn_mfma_f32_16x16x32_bf16(af[fr], bfr[fc], acc[fr][fc], 0, 0, 0);
    }
  }
  // C/D frag map (verified m89/m91): col = lane&15, row = (lane>>4)*4 + reg

  if constexpr (EPI == 0) {
    __shared__ float rsum[64][4];
#pragma unroll
    for (int fr = 0; fr < 4; ++fr) {
      int rb = i0 + fr * 16 + g * 4;
      float sr[4] = {0.f, 0.f, 0.f, 0.f};
#pragma unroll
      for (int fc = 0; fc < 4; ++fc) {
        int j = n0 + w * 64 + fc * 16 + l4;
#pragma unroll
        for (int reg = 0; reg < 4; ++reg) {
          int i = rb + reg;
          float v = fabsf(acc[fr][fc][reg]);
          if (i < N_ && j < N_) outF[((size_t)b * N_ + i) * N_ + j] = v;
          if (i < N_ && j < 288) outB[((size_t)b * N_ + i) * 288 + j] = f2bf(j < N_ ? v : 0.f);
          if (j < N_) sr[reg] += v;
        }
      }
#pragma unroll
      for (int reg = 0; reg < 4; ++reg) {
        float s = sr[reg];
        s += __shfl_xor(s, 1); s += __shfl_xor(s, 2);
        s += __shfl_xor(s, 4); s += __shfl_xor(s, 8);
        if (l4 == 0) rsum[fr * 16 + g * 4 + reg][w] = s;
      }
    }
    __syncthreads();
    if (tid < 64) {
      int i = i0 + tid;
      if (i < N_)
        atomicAdd(&dsum[(size_t)b * N_ + i],
                  rsum[tid][0] + rsum[tid][1] + rsum[tid][2] + rsum[tid][3]);
    }
  }

  if constexpr (EPI == 1) {
#pragma unroll
    for (int fr = 0; fr < 4; ++fr) {
      int rb = i0 + fr * 16 + g * 4;
      if (rb < 288) {
        float dv[4];
#pragma unroll
        for (int reg = 0; reg < 4; ++reg) {
          int j = rb + reg;
          dv[reg] = (j < N_) ? (1.f / sqrtf(1.f + dsum[(size_t)b * N_ + j])) : 0.f;  // pad rows exact 0
        }
#pragma unroll
        for (int fc = 0; fc < 4; ++fc) {
          int col = w * 64 + fc * 16 + l4;
          ushort4v pk;
#pragma unroll
          for (int reg = 0; reg < 4; ++reg)
            pk[reg] = f2bf(dv[reg] * acc[fr][fc][reg]);
          *(ushort4v*)(outB + ((size_t)b * H_ + col) * 288 + rb) = pk;
        }
      }
    }
  }

  if constexpr (EPI >= 2) {
    __shared__ float rs[64][4];
    float ratio[4][4];
    // X = dinv_i * (acc + YT[col][i]) + bias[col]   (diag of L folded via YT)
#pragma unroll
    for (int fr = 0; fr < 4; ++fr) {
      int rb = i0 + fr * 16 + g * 4;
      int rbc = min(rb, 284);                // clamped dy read (clamped rows discarded)
      float din[4];
#pragma unroll
      for (int reg = 0; reg < 4; ++reg) {
        int ic = min(rb + reg, N_ - 1);
        din[reg] = 1.f / sqrtf(1.f + dsum[(size_t)b * N_ + ic]);
      }
#pragma unroll
      for (int fc = 0; fc < 4; ++fc) {
        int col = w * 64 + fc * 16 + l4;
        ushort4v dy = *(const ushort4v*)(Bb + (size_t)col * ldb + rbc);
        float bias_v = bias[col];
#pragma unroll
        for (int reg = 0; reg < 4; ++reg) {
          float x = din[reg] * (acc[fr][fc][reg] + bf2f(dy[reg])) + bias_v;
          acc[fr][fc][reg] = x;
        }
      }
    }
    // per-row sum of x^2: in-lane over fc, shfl over 16-lane col group, LDS over waves
#pragma unroll
    for (int fr = 0; fr < 4; ++fr) {
#pragma unroll
      for (int reg = 0; reg < 4; ++reg) {
        float s = 0.f;
#pragma unroll
        for (int fc = 0; fc < 4; ++fc) { float x = acc[fr][fc][reg]; s += x * x; }
        s += __shfl_xor(s, 1); s += __shfl_xor(s, 2);
        s += __shfl_xor(s, 4); s += __shfl_xor(s, 8);
        if (l4 == 0) rs[fr * 16 + g * 4 + reg][w] = s;
      }
    }
    __syncthreads();
#pragma unroll
    for (int fr = 0; fr < 4; ++fr)
#pragma unroll
      for (int reg = 0; reg < 4; ++reg) {
        int r = fr * 16 + g * 4 + reg;
        float tot = rs[r][0] + rs[r][1] + rs[r][2] + rs[r][3];
        float norm = fmaxf(sqrtf(tot), 1e-15f);
        float scale = (norm > MAXNORM_) ? (MAXNORM_ / norm) : 1.0f;
        float pn = fmaxf(fminf(norm, MAXNORM_), 1e-15f);
        ratio[fr][reg] = atanhf(pn) / pn * scale;
      }
#pragma unroll
    for (int fr = 0; fr < 4; ++fr) {
      int rb = i0 + fr * 16 + g * 4;
#pragma unroll
      for (int fc = 0; fc < 4; ++fc) {
        int col = w * 64 + fc * 16 + l4;
#pragma unroll
        for (int reg = 0; reg < 4; ++reg) {
          int row = rb + reg;
          if (row < N_) {
            float y = ratio[fr][reg] * acc[fr][fc][reg];
            float o = fmaxf(y, 0.f) + 0.5f * __cosf(y + PHI_);
            if constexpr (EPI == 2) outB[((size_t)b * N_ + row) * H_ + col] = f2bf(o);
            else                    outF[((size_t)b * N_ + row) * H_ + col] = o;
          }
        }
      }
    }
  }
}

// ---------------------------------------------------------------------------
extern "C" void kernel_launch(void* const* d_in, const int* in_sizes, int n_in,
                              void* d_out, int out_size, void* d_ws, size_t ws_size,
                              hipStream_t stream) {
  const float* data = (const float*)d_in[0];
  const float* W1   = (const float*)d_in[1];
  const float* b1   = (const float*)d_in[2];
  const float* W2   = (const float*)d_in[3];
  const float* b2   = (const float*)d_in[4];

  float* g2   = (float*)d_out;                          // [B,N,H] f32
  float* adjF = g2 + (size_t)B_ * N_ * H_;              // [B,N,N] f32

  float* ws_f = (float*)d_ws;
  float* dsum = ws_f;                                   // BN row-sums (atomic)
  unsigned short* region1 = (unsigned short*)(ws_f + BN_);
  unsigned short* z    = region1;                       // [BN][256], dead after corr
  unsigned short* YT   = region1;                       // [B*256][288], reused layer2
  unsigned short* W1T  = region1 + (size_t)B_ * H_ * 288;   // [256][288]
  unsigned short* W2T  = W1T + (size_t)H_ * 288;            // [256][256]
  unsigned short* adjB = W2T + (size_t)H_ * H_;             // [B][264][288]
  unsigned short* g1bf = (unsigned short*)d_out;        // scratch inside g2 region

  hipMemsetAsync(dsum, 0, BN_ * sizeof(float), stream);
  zTs_kernel<<<dim3(5, B_), 256, 0, stream>>>(data, z);
  wtrans_kernel<<<dim3(5, 4), 256, 0, stream>>>(W1, W1T, N_, 288);
  wtrans_kernel<<<dim3(4, 4), 256, 0, stream>>>(W2, W2T, H_, 256);
  // adj = |z z^T| (+ bf16 copy, k-padded; + dinv row-sum partials)
  mfma_gemm_kernel<0><<<dim3(2, 5, B_), 256, 0, stream>>>(
      z, 256, (long)N_ * 256, N_, z, 256, (long)N_ * 256, N_, 8,
      adjF, adjB, dsum, nullptr);
  // Y1T[h][j] = rsqrt(1+dsum_j) * (adj @ W1)[j][h]
  mfma_gemm_kernel<1><<<dim3(1, 5, B_), 256, 0, stream>>>(
      adjB, 288, (long)N_ * 288, N_, W1T, 288, 0L, 256, 9,
      nullptr, YT, dsum, nullptr);
  // g1 = act(fkernel(dinv_i*(adj @ Y1T^T + diag) + b1))
  mfma_gemm_kernel<2><<<dim3(1, 5, B_), 256, 0, stream>>>(
      adjB, 288, (long)N_ * 288, N_, YT, 288, (long)H_ * 288, 256, 9,
      nullptr, g1bf, dsum, b1);
  // Y2T[h][j] = rsqrt(1+dsum_j) * (g1 @ W2)[j][h]
  mfma_gemm_kernel<1><<<dim3(1, 5, B_), 256, 0, stream>>>(
      g1bf, 256, (long)N_ * 256, N_, W2T, 256, 0L, 256, 8,
      nullptr, YT, dsum, nullptr);
  // g2 = act(fkernel(...)) -> final f32 output
  mfma_gemm_kernel<3><<<dim3(1, 5, B_), 256, 0, stream>>>(
      adjB, 288, (long)N_ * 288, N_, YT, 288, (long)H_ * 288, 256, 9,
      g2, nullptr, dsum, b2);
}

// Round 6
// 602.158 us; speedup vs baseline: 1.2133x; 1.2133x over previous
//
#include <hip/hip_runtime.h>
#include <hip/hip_bf16.h>
#include <math.h>

#define B_ 256
#define T_ 240
#define N_ 264
#define H_ 256
#define BN_ (B_ * N_)
#define PHI_ 0.94247778f   // 3.1415926 * 0.3
#define MAXNORM_ 0.996f    // (1 - 4e-3)/sqrt(c), c=1

typedef short short8 __attribute__((ext_vector_type(8)));     // 8 bf16 (4 VGPRs) MFMA A/B frag
typedef float f32x4 __attribute__((ext_vector_type(4)));      // MFMA C/D frag
typedef unsigned short ushort4v __attribute__((ext_vector_type(4)));

__device__ inline unsigned short f2bf(float f) {
  __hip_bfloat16 h = __float2bfloat16(f);
  return *reinterpret_cast<unsigned short*>(&h);
}
__device__ inline float bf2f(unsigned short u) {
  unsigned int x = ((unsigned int)u) << 16;
  return __uint_as_float(x);
}

// Conflict-free 16B-granule LDS placement (read side).
// swz16(row,kg) = row*4 + (kg ^ (row>>1))&3. Inverse (write side, linear slot s):
// row = s>>2, kg = (s&3) ^ ((s>>3)&3)  [algebra: (s>>3)&3 == (row>>1)&3].
__device__ inline int swz16(int row, int kg) {
  return row * 4 + ((kg ^ (row >> 1)) & 3);
}

// Async global->LDS, 16B per lane, LDS dest = wave-uniform base + lane*16.
__device__ inline void gload_lds16(const void* g, void* l) {
  __builtin_amdgcn_global_load_lds(
      (const __attribute__((address_space(1))) unsigned int*)g,
      (__attribute__((address_space(3))) unsigned int*)l, 16, 0, 0);
}

// ---------------------------------------------------------------------------
// Kernel 1: fused stats + transposed normalize:
// z[b][n][t] = bf16((data[b][t][n]-mean_n)*rdev_n), t in [0,256), t>=240 -> 0
// ---------------------------------------------------------------------------
__global__ __launch_bounds__(256) void zTs_kernel(
    const float* __restrict__ data, unsigned short* __restrict__ z) {
  int b = blockIdx.y;
  int n0 = blockIdx.x * 64;
  __shared__ float ld[240 * 65];          // [t][col], stride 65 -> conflict-free both axes
  __shared__ float ps[4][64], pq[4][64];
  __shared__ float mS[64], rS[64];
  int tid = threadIdx.x, lane = tid & 63, wv = tid >> 6;
  int n = n0 + lane;
  bool nv = n < N_;
  for (int t = wv; t < T_; t += 4)
    ld[t * 65 + lane] = nv ? data[((size_t)b * T_ + t) * N_ + n] : 0.f;
  __syncthreads();
  {
    int col = tid & 63, q = tid >> 6;
    float s = 0.f, ss = 0.f;
    for (int t = q * 60; t < q * 60 + 60; ++t) { float v = ld[t * 65 + col]; s += v; ss += v * v; }
    ps[q][col] = s; pq[q][col] = ss;
  }
  __syncthreads();
  if (tid < 64) {
    float s  = ps[0][tid] + ps[1][tid] + ps[2][tid] + ps[3][tid];
    float ss = pq[0][tid] + pq[1][tid] + pq[2][tid] + pq[3][tid];
    float m = s / (float)T_;
    float var = ss - s * m;
    float d = sqrtf(fmaxf(var, 0.f));
    mS[tid] = m;
    rS[tid] = (d > 0.f) ? (1.f / d) : 0.f;   // nan_to_num semantics
  }
  __syncthreads();
  int nrows = min(64, N_ - n0);
  for (int rr = 0; rr < nrows; ++rr) {
    float m = mS[rr], r = rS[rr];
    unsigned short val = (tid < T_) ? f2bf((ld[tid * 65 + rr] - m) * r) : (unsigned short)0;
    z[((size_t)(b * N_ + n0 + rr)) * 256 + tid] = val;
  }
}

// ---------------------------------------------------------------------------
// Kernel 2: WT[h][j] = bf16(W[j][h]), j-pad to Jpad with zeros
// ---------------------------------------------------------------------------
__global__ __launch_bounds__(256) void wtrans_kernel(
    const float* __restrict__ W, unsigned short* __restrict__ WT,
    int Jv, int Jpad) {
  int jt = blockIdx.x * 64, ht = blockIdx.y * 64;
  __shared__ float tile[64][65];
  int tid = threadIdx.x;
  for (int idx = tid; idx < 4096; idx += 256) {
    int jr = idx >> 6, hr = idx & 63;
    int j = jt + jr;
    tile[jr][hr] = (j < Jv) ? W[(size_t)j * H_ + ht + hr] : 0.f;
  }
  __syncthreads();
  for (int idx = tid; idx < 4096; idx += 256) {
    int hr = idx >> 6, jr = idx & 63;
    int j = jt + jr;
    if (j < Jpad) WT[(size_t)(ht + hr) * Jpad + j] = f2bf(tile[jr][hr]);
  }
}

// ---------------------------------------------------------------------------
// MFMA GEMM template: C[64 x 256] tile per block, 4 waves, K-step 32,
// double-buffered LDS with global_load_lds prefetch (one barrier per step;
// load latency hidden under ds_read+MFMA of the current step).
// A row-major [rowsA][lda] bf16 (row-clamped), B^T row-major [ldb-stride] bf16.
// OOB B-rows (corr bx=1 only) read garbage from allocated ws; their columns
// are discarded in the epilogue (independent dot products -> no contamination).
// EPI 0: corr -> adjF f32 + adjB bf16 [264][288]; row-sum partials -> dsum (atomic)
// EPI 1: aw   -> YT bf16 [256][288]: YT[h][j] = rsqrt(1+dsum_j) * acc (pad 0)
// EPI 2: lx   -> g1 bf16 [264][256], fused bias + L-diag + project/logmap/act
// EPI 3: lx   -> g2 f32  [264][256], same epilogue
// Block ids XCD-remapped (bijective, nwg % 8 == 0 for all grids).
// ---------------------------------------------------------------------------
template<int EPI>
__global__ __launch_bounds__(256) void mfma_gemm_kernel(
    const unsigned short* __restrict__ A, int lda, long sA, int rowsA,
    const unsigned short* __restrict__ Bm, int ldb, long sB, int validB,
    int ksteps,
    float* __restrict__ outF, unsigned short* __restrict__ outB,
    float* __restrict__ dsum, const float* __restrict__ bias) {
  // XCD-aware remap: consecutive work-ids (same batch) -> same XCD chunk
  int gx = gridDim.x, gy = gridDim.y;
  int flat = (blockIdx.z * gy + blockIdx.y) * gx + blockIdx.x;
  int nwg = gx * gy * gridDim.z;
  int q8 = nwg >> 3;
  int id = (flat & 7) * q8 + (flat >> 3);
  int bx = id % gx; int tq = id / gx;
  int b = tq / gy;
  int i0 = (tq % gy) * 64;
  int n0 = bx * 256;

  int tid = threadIdx.x;
  int w = tid >> 6, lane = tid & 63, g = lane >> 4, l4 = lane & 15;

  __shared__ short8 AsV[2][256];    // 16B granules, swizzled content : 2 x 4 KB
  __shared__ short8 BsV[2][1024];   //                              : 2 x 16 KB

  const unsigned short* Ab = A + (size_t)b * sA;
  const unsigned short* Bb = Bm + (size_t)b * sB;

  f32x4 acc[4][4];
#pragma unroll
  for (int x = 0; x < 4; ++x)
#pragma unroll
    for (int y = 0; y < 4; ++y) acc[x][y] = (f32x4){0.f, 0.f, 0.f, 0.f};

  // Per-lane pre-swizzled global sources (inverse of swz16) so the linear
  // lane-order LDS write of global_load_lds lands data where swz16 reads it.
  const unsigned short* aSrc;
  {
    int s = w * 64 + lane;                       // A slot this lane fills
    int row = s >> 2, kg = (s & 3) ^ ((s >> 3) & 3);
    int rA = min(i0 + row, rowsA - 1);           // clamp (dup rows discarded later)
    aSrc = Ab + (size_t)rA * lda + kg * 8;
  }
  const unsigned short* bSrc[4];
#pragma unroll
  for (int c = 0; c < 4; ++c) {
    int s = w * 256 + c * 64 + lane;             // B slot this lane fills
    int col = s >> 2, kg = (s & 3) ^ ((s >> 3) & 3);
    bSrc[c] = Bb + (size_t)(n0 + col) * ldb + kg * 8;
  }
  bool wactive = (n0 + w * 64) < validB;         // corr bx=1: waves 1-3 fully invalid

  // prologue: stage k-step 0 into buf 0
  gload_lds16(aSrc, &AsV[0][w * 64]);
#pragma unroll
  for (int c = 0; c < 4; ++c) gload_lds16(bSrc[c], &BsV[0][w * 256 + c * 64]);
  __syncthreads();

  int cur = 0;
  for (int ks = 0; ks < ksteps; ++ks) {
    if (ks + 1 < ksteps) {               // stage next step into the other buffer
      int k1 = (ks + 1) * 32;
      gload_lds16(aSrc + k1, &AsV[cur ^ 1][w * 64]);
#pragma unroll
      for (int c = 0; c < 4; ++c) gload_lds16(bSrc[c] + k1, &BsV[cur ^ 1][w * 256 + c * 64]);
    }
    if (wactive) {
      short8 af[4], bfr[4];
#pragma unroll
      for (int fr = 0; fr < 4; ++fr) af[fr] = AsV[cur][swz16(fr * 16 + l4, g)];
#pragma unroll
      for (int fc = 0; fc < 4; ++fc) bfr[fc] = BsV[cur][swz16(w * 64 + fc * 16 + l4, g)];
#pragma unroll
      for (int fr = 0; fr < 4; ++fr)
#pragma unroll
        for (int fc = 0; fc < 4; ++fc)
          acc[fr][fc] = __builtin_amdgcn_mfma_f32_16x16x32_bf16(af[fr], bfr[fc], acc[fr][fc], 0, 0, 0);
    }
    __syncthreads();   // compiler-emitted vmcnt(0) drains the prefetch; one barrier/step
    cur ^= 1;
  }
  // C/D frag map (verified m89/m91): col = lane&15, row = (lane>>4)*4 + reg

  if constexpr (EPI == 0) {
    __shared__ float rsum[64][4];
#pragma unroll
    for (int fr = 0; fr < 4; ++fr) {
      int rb = i0 + fr * 16 + g * 4;
      float sr[4] = {0.f, 0.f, 0.f, 0.f};
#pragma unroll
      for (int fc = 0; fc < 4; ++fc) {
        int j = n0 + w * 64 + fc * 16 + l4;
#pragma unroll
        for (int reg = 0; reg < 4; ++reg) {
          int i = rb + reg;
          float v = fabsf(acc[fr][fc][reg]);
          if (i < N_ && j < N_) outF[((size_t)b * N_ + i) * N_ + j] = v;
          if (i < N_ && j < 288) outB[((size_t)b * N_ + i) * 288 + j] = f2bf(j < N_ ? v : 0.f);
          if (j < N_) sr[reg] += v;
        }
      }
#pragma unroll
      for (int reg = 0; reg < 4; ++reg) {
        float s = sr[reg];
        s += __shfl_xor(s, 1); s += __shfl_xor(s, 2);
        s += __shfl_xor(s, 4); s += __shfl_xor(s, 8);
        if (l4 == 0) rsum[fr * 16 + g * 4 + reg][w] = s;
      }
    }
    __syncthreads();
    if (tid < 64) {
      int i = i0 + tid;
      if (i < N_)
        atomicAdd(&dsum[(size_t)b * N_ + i],
                  rsum[tid][0] + rsum[tid][1] + rsum[tid][2] + rsum[tid][3]);
    }
  }

  if constexpr (EPI == 1) {
#pragma unroll
    for (int fr = 0; fr < 4; ++fr) {
      int rb = i0 + fr * 16 + g * 4;
      if (rb < 288) {
        float dv[4];
#pragma unroll
        for (int reg = 0; reg < 4; ++reg) {
          int j = rb + reg;
          dv[reg] = (j < N_) ? (1.f / sqrtf(1.f + dsum[(size_t)b * N_ + j])) : 0.f;  // pad rows exact 0
        }
#pragma unroll
        for (int fc = 0; fc < 4; ++fc) {
          int col = w * 64 + fc * 16 + l4;
          ushort4v pk;
#pragma unroll
          for (int reg = 0; reg < 4; ++reg)
            pk[reg] = f2bf(dv[reg] * acc[fr][fc][reg]);
          *(ushort4v*)(outB + ((size_t)b * H_ + col) * 288 + rb) = pk;
        }
      }
    }
  }

  if constexpr (EPI >= 2) {
    __shared__ float rs[64][4];
    float ratio[4][4];
    // X = dinv_i * (acc + YT[col][i]) + bias[col]   (diag of L folded via YT)
#pragma unroll
    for (int fr = 0; fr < 4; ++fr) {
      int rb = i0 + fr * 16 + g * 4;
      int rbc = min(rb, 284);                // clamped dy read (clamped rows discarded)
      float din[4];
#pragma unroll
      for (int reg = 0; reg < 4; ++reg) {
        int ic = min(rb + reg, N_ - 1);
        din[reg] = 1.f / sqrtf(1.f + dsum[(size_t)b * N_ + ic]);
      }
#pragma unroll
      for (int fc = 0; fc < 4; ++fc) {
        int col = w * 64 + fc * 16 + l4;
        ushort4v dy = *(const ushort4v*)(Bb + (size_t)col * ldb + rbc);
        float bias_v = bias[col];
#pragma unroll
        for (int reg = 0; reg < 4; ++reg) {
          float x = din[reg] * (acc[fr][fc][reg] + bf2f(dy[reg])) + bias_v;
          acc[fr][fc][reg] = x;
        }
      }
    }
    // per-row sum of x^2: in-lane over fc, shfl over 16-lane col group, LDS over waves
#pragma unroll
    for (int fr = 0; fr < 4; ++fr) {
#pragma unroll
      for (int reg = 0; reg < 4; ++reg) {
        float s = 0.f;
#pragma unroll
        for (int fc = 0; fc < 4; ++fc) { float x = acc[fr][fc][reg]; s += x * x; }
        s += __shfl_xor(s, 1); s += __shfl_xor(s, 2);
        s += __shfl_xor(s, 4); s += __shfl_xor(s, 8);
        if (l4 == 0) rs[fr * 16 + g * 4 + reg][w] = s;
      }
    }
    __syncthreads();
#pragma unroll
    for (int fr = 0; fr < 4; ++fr)
#pragma unroll
      for (int reg = 0; reg < 4; ++reg) {
        int r = fr * 16 + g * 4 + reg;
        float tot = rs[r][0] + rs[r][1] + rs[r][2] + rs[r][3];
        float norm = fmaxf(sqrtf(tot), 1e-15f);
        float scale = (norm > MAXNORM_) ? (MAXNORM_ / norm) : 1.0f;
        float pn = fmaxf(fminf(norm, MAXNORM_), 1e-15f);
        ratio[fr][reg] = atanhf(pn) / pn * scale;
      }
#pragma unroll
    for (int fr = 0; fr < 4; ++fr) {
      int rb = i0 + fr * 16 + g * 4;
#pragma unroll
      for (int fc = 0; fc < 4; ++fc) {
        int col = w * 64 + fc * 16 + l4;
#pragma unroll
        for (int reg = 0; reg < 4; ++reg) {
          int row = rb + reg;
          if (row < N_) {
            float y = ratio[fr][reg] * acc[fr][fc][reg];
            float o = fmaxf(y, 0.f) + 0.5f * __cosf(y + PHI_);
            if constexpr (EPI == 2) outB[((size_t)b * N_ + row) * H_ + col] = f2bf(o);
            else                    outF[((size_t)b * N_ + row) * H_ + col] = o;
          }
        }
      }
    }
  }
}

// ---------------------------------------------------------------------------
extern "C" void kernel_launch(void* const* d_in, const int* in_sizes, int n_in,
                              void* d_out, int out_size, void* d_ws, size_t ws_size,
                              hipStream_t stream) {
  const float* data = (const float*)d_in[0];
  const float* W1   = (const float*)d_in[1];
  const float* b1   = (const float*)d_in[2];
  const float* W2   = (const float*)d_in[3];
  const float* b2   = (const float*)d_in[4];

  float* g2   = (float*)d_out;                          // [B,N,H] f32
  float* adjF = g2 + (size_t)B_ * N_ * H_;              // [B,N,N] f32

  float* ws_f = (float*)d_ws;
  float* dsum = ws_f;                                   // BN row-sums (atomic)
  unsigned short* region1 = (unsigned short*)(ws_f + BN_);
  unsigned short* z    = region1;                       // [BN][256], dead after corr
  unsigned short* YT   = region1;                       // [B*256][288], reused layer2
  unsigned short* W1T  = region1 + (size_t)B_ * H_ * 288;   // [256][288]
  unsigned short* W2T  = W1T + (size_t)H_ * 288;            // [256][256]
  unsigned short* adjB = W2T + (size_t)H_ * H_;             // [B][264][288]
  unsigned short* g1bf = (unsigned short*)d_out;        // scratch inside g2 region

  hipMemsetAsync(dsum, 0, BN_ * sizeof(float), stream);
  zTs_kernel<<<dim3(5, B_), 256, 0, stream>>>(data, z);
  wtrans_kernel<<<dim3(5, 4), 256, 0, stream>>>(W1, W1T, N_, 288);
  wtrans_kernel<<<dim3(4, 4), 256, 0, stream>>>(W2, W2T, H_, 256);
  // adj = |z z^T| (+ bf16 copy, k-padded; + dinv row-sum partials)
  mfma_gemm_kernel<0><<<dim3(2, 5, B_), 256, 0, stream>>>(
      z, 256, (long)N_ * 256, N_, z, 256, (long)N_ * 256, N_, 8,
      adjF, adjB, dsum, nullptr);
  // Y1T[h][j] = rsqrt(1+dsum_j) * (adj @ W1)[j][h]
  mfma_gemm_kernel<1><<<dim3(1, 5, B_), 256, 0, stream>>>(
      adjB, 288, (long)N_ * 288, N_, W1T, 288, 0L, 256, 9,
      nullptr, YT, dsum, nullptr);
  // g1 = act(fkernel(dinv_i*(adj @ Y1T^T + diag) + b1))
  mfma_gemm_kernel<2><<<dim3(1, 5, B_), 256, 0, stream>>>(
      adjB, 288, (long)N_ * 288, N_, YT, 288, (long)H_ * 288, 256, 9,
      nullptr, g1bf, dsum, b1);
  // Y2T[h][j] = rsqrt(1+dsum_j) * (g1 @ W2)[j][h]
  mfma_gemm_kernel<1><<<dim3(1, 5, B_), 256, 0, stream>>>(
      g1bf, 256, (long)N_ * 256, N_, W2T, 256, 0L, 256, 8,
      nullptr, YT, dsum, nullptr);
  // g2 = act(fkernel(...)) -> final f32 output
  mfma_gemm_kernel<3><<<dim3(1, 5, B_), 256, 0, stream>>>(
      adjB, 288, (long)N_ * 288, N_, YT, 288, (long)H_ * 288, 256, 9,
      g2, nullptr, dsum, b2);
}

// Round 8
// 554.767 us; speedup vs baseline: 1.3169x; 1.0854x over previous
//
#include <hip/hip_runtime.h>
#include <hip/hip_bf16.h>
#include <math.h>

#define B_ 256
#define T_ 240
#define N_ 264
#define H_ 256
#define BN_ (B_ * N_)
#define PHI_ 0.94247778f   // 3.1415926 * 0.3
#define MAXNORM_ 0.996f    // (1 - 4e-3)/sqrt(c), c=1

typedef short short8 __attribute__((ext_vector_type(8)));     // 8 bf16 (4 VGPRs) MFMA A/B frag
typedef float f32x4 __attribute__((ext_vector_type(4)));      // MFMA C/D frag
typedef unsigned short ushort4v __attribute__((ext_vector_type(4)));

__device__ inline unsigned short f2bf(float f) {
  __hip_bfloat16 h = __float2bfloat16(f);
  return *reinterpret_cast<unsigned short*>(&h);
}
__device__ inline float bf2f(unsigned short u) {
  unsigned int x = ((unsigned int)u) << 16;
  return __uint_as_float(x);
}

// Conflict-free 16B-granule LDS placement (read side).
// swz16(row,kg) = row*4 + (kg ^ (row>>1))&3. Inverse (write side, linear slot s):
// row = s>>2, kg = (s&3) ^ ((s>>3)&3).
__device__ inline int swz16(int row, int kg) {
  return row * 4 + ((kg ^ (row >> 1)) & 3);
}

// Async global->LDS, 16B per lane, LDS dest = wave-uniform base + lane*16.
__device__ inline void gload_lds16(const void* g, void* l) {
  __builtin_amdgcn_global_load_lds(
      (const __attribute__((address_space(1))) unsigned int*)g,
      (__attribute__((address_space(3))) unsigned int*)l, 16, 0, 0);
}

// ---------------------------------------------------------------------------
// Kernel 1a: per-(b,n) mean and 1/std over T (single pass, coalesced)
// ---------------------------------------------------------------------------
__global__ __launch_bounds__(512) void stats2_kernel(
    const float* __restrict__ data, float* __restrict__ mean, float* __restrict__ rd) {
  int b = blockIdx.x;
  int n = threadIdx.x;
  if (n >= N_) return;
  const float* db = data + (size_t)b * T_ * N_ + n;
  float s = 0.f, ss = 0.f;
#pragma unroll 8
  for (int t = 0; t < T_; ++t) {
    float v = db[(size_t)t * N_];
    s += v; ss += v * v;
  }
  float m = s / (float)T_;
  float var = ss - s * m;
  float d = sqrtf(fmaxf(var, 0.f));
  mean[b * N_ + n] = m;
  rd[b * N_ + n] = (d > 0.f) ? (1.f / d) : 0.f;   // nan_to_num semantics
}

// ---------------------------------------------------------------------------
// Kernel 1b: transposed normalize, tiled:
// z[b][n][t] = bf16((data[b][t][n]-mean_n)*rd_n), t in [0,256), t>=240 -> 0
// 64n x 64t f32 tile (16.6 KB LDS, ~8 blocks/CU), vectorized short4 stores:
// per store instruction a wave writes 4 complete 128B row-chunks.
// ---------------------------------------------------------------------------
__global__ __launch_bounds__(256) void ztile_kernel(
    const float* __restrict__ data, const float* __restrict__ mean,
    const float* __restrict__ rd, unsigned short* __restrict__ z) {
  int b = blockIdx.y, n0 = blockIdx.x * 64;
  __shared__ float tile[64][65];
  __shared__ float mS[64], rS[64];
  int tid = threadIdx.x;
  if (tid < 64) {
    int n = n0 + tid;
    mS[tid] = (n < N_) ? mean[b * N_ + n] : 0.f;
    rS[tid] = (n < N_) ? rd[b * N_ + n] : 0.f;
  }
  const float* db = data + (size_t)b * T_ * N_;
  int e = tid & 15, rbase = tid >> 4;   // write map: 16 lanes cover one 128B row-chunk
  for (int sub = 0; sub < 4; ++sub) {
    int t0 = sub * 64;
    __syncthreads();                    // mS ready (iter 0) / prev readers done
    for (int idx = tid; idx < 4096; idx += 256) {
      int tl = idx >> 6, nl = idx & 63;
      int t = t0 + tl, n = n0 + nl;
      tile[tl][nl] = (t < T_ && n < N_) ? db[(size_t)t * N_ + n] : 0.f;
    }
    __syncthreads();
#pragma unroll
    for (int i = 0; i < 4; ++i) {
      int r = rbase + 16 * i;
      int n_r = n0 + r;
      if (n_r < N_) {
        float m = mS[r], rr_ = rS[r];
        ushort4v pk;
#pragma unroll
        for (int j = 0; j < 4; ++j) {
          int tl = e * 4 + j;
          pk[j] = (t0 + tl < T_) ? f2bf((tile[tl][r] - m) * rr_) : (unsigned short)0;
        }
        *(ushort4v*)(z + ((size_t)(b * N_ + n_r)) * 256 + t0 + e * 4) = pk;
      }
    }
  }
}

// ---------------------------------------------------------------------------
// Kernel 2: WT[h][j] = bf16(W[j][h]), j-pad to Jpad with zeros
// ---------------------------------------------------------------------------
__global__ __launch_bounds__(256) void wtrans_kernel(
    const float* __restrict__ W, unsigned short* __restrict__ WT,
    int Jv, int Jpad) {
  int jt = blockIdx.x * 64, ht = blockIdx.y * 64;
  __shared__ float tile[64][65];
  int tid = threadIdx.x;
  for (int idx = tid; idx < 4096; idx += 256) {
    int jr = idx >> 6, hr = idx & 63;
    int j = jt + jr;
    tile[jr][hr] = (j < Jv) ? W[(size_t)j * H_ + ht + hr] : 0.f;
  }
  __syncthreads();
  for (int idx = tid; idx < 4096; idx += 256) {
    int hr = idx >> 6, jr = idx & 63;
    int j = jt + jr;
    if (j < Jpad) WT[(size_t)(ht + hr) * Jpad + j] = f2bf(tile[jr][hr]);
  }
}

// ---------------------------------------------------------------------------
// MFMA GEMM template: C[64 x 256] tile per block, 4 waves, K-step 32,
// double-buffered LDS with global_load_lds prefetch (one barrier per step).
// A row-major [rowsA][lda] bf16 (row-clamped), B^T row-major [ldb-stride] bf16.
// Waves whose 64-col span is entirely >= validB skip B staging AND compute.
// EPI 0: corr -> adjF f32 + adjB bf16 [264][288]; row-sum partials -> dsum (atomic)
// EPI 1: aw   -> YT bf16 [256][288]: YT[h][j] = rsqrt(1+dsum_j) * acc (pad 0)
// EPI 2: lx   -> g1 bf16 [264][256], fused bias + L-diag + project/logmap/act
// EPI 3: lx   -> g2 f32  [264][256], same epilogue
// Block ids XCD-remapped (bijective, nwg % 8 == 0 for all grids).
// ---------------------------------------------------------------------------
template<int EPI>
__global__ __launch_bounds__(256) void mfma_gemm_kernel(
    const unsigned short* __restrict__ A, int lda, long sA, int rowsA,
    const unsigned short* __restrict__ Bm, int ldb, long sB, int validB,
    int ksteps,
    float* __restrict__ outF, unsigned short* __restrict__ outB,
    float* __restrict__ dsum, const float* __restrict__ bias) {
  // XCD-aware remap: consecutive work-ids (same batch) -> same XCD chunk
  int gx = gridDim.x, gy = gridDim.y;
  int flat = (blockIdx.z * gy + blockIdx.y) * gx + blockIdx.x;
  int nwg = gx * gy * gridDim.z;
  int q8 = nwg >> 3;
  int id = (flat & 7) * q8 + (flat >> 3);
  int bx = id % gx; int tq = id / gx;
  int b = tq / gy;
  int i0 = (tq % gy) * 64;
  int n0 = bx * 256;

  int tid = threadIdx.x;
  int w = tid >> 6, lane = tid & 63, g = lane >> 4, l4 = lane & 15;

  __shared__ short8 AsV[2][256];    // 16B granules, swizzled content : 2 x 4 KB
  __shared__ short8 BsV[2][1024];   //                               : 2 x 16 KB

  const unsigned short* Ab = A + (size_t)b * sA;
  const unsigned short* Bb = Bm + (size_t)b * sB;

  f32x4 acc[4][4];
#pragma unroll
  for (int x = 0; x < 4; ++x)
#pragma unroll
    for (int y = 0; y < 4; ++y) acc[x][y] = (f32x4){0.f, 0.f, 0.f, 0.f};

  // Per-lane pre-swizzled global sources (inverse of swz16) so the linear
  // lane-order LDS write of global_load_lds lands data where swz16 reads it.
  const unsigned short* aSrc;
  {
    int s = w * 64 + lane;                       // A slot this lane fills
    int row = s >> 2, kg = (s & 3) ^ ((s >> 3) & 3);
    int rA = min(i0 + row, rowsA - 1);           // clamp (dup rows discarded later)
    aSrc = Ab + (size_t)rA * lda + kg * 8;
  }
  const unsigned short* bSrc[4];
#pragma unroll
  for (int c = 0; c < 4; ++c) {
    int s = w * 256 + c * 64 + lane;             // B slot this lane fills
    int col = s >> 2, kg = (s & 3) ^ ((s >> 3) & 3);
    bSrc[c] = Bb + (size_t)(n0 + col) * ldb + kg * 8;
  }
  bool wactive = (n0 + w * 64) < validB;         // corr bx=1: waves 1-3 fully invalid

  // prologue: stage k-step 0 into buf 0
  gload_lds16(aSrc, &AsV[0][w * 64]);
  if (wactive) {
#pragma unroll
    for (int c = 0; c < 4; ++c) gload_lds16(bSrc[c], &BsV[0][w * 256 + c * 64]);
  }
  __syncthreads();

  int cur = 0;
  for (int ks = 0; ks < ksteps; ++ks) {
    if (ks + 1 < ksteps) {               // stage next step into the other buffer
      int k1 = (ks + 1) * 32;
      gload_lds16(aSrc + k1, &AsV[cur ^ 1][w * 64]);
      if (wactive) {
#pragma unroll
        for (int c = 0; c < 4; ++c) gload_lds16(bSrc[c] + k1, &BsV[cur ^ 1][w * 256 + c * 64]);
      }
    }
    if (wactive) {
      short8 af[4], bfr[4];
#pragma unroll
      for (int fr = 0; fr < 4; ++fr) af[fr] = AsV[cur][swz16(fr * 16 + l4, g)];
#pragma unroll
      for (int fc = 0; fc < 4; ++fc) bfr[fc] = BsV[cur][swz16(w * 64 + fc * 16 + l4, g)];
#pragma unroll
      for (int fr = 0; fr < 4; ++fr)
#pragma unroll
        for (int fc = 0; fc < 4; ++fc)
          acc[fr][fc] = __builtin_amdgcn_mfma_f32_16x16x32_bf16(af[fr], bfr[fc], acc[fr][fc], 0, 0, 0);
    }
    __syncthreads();   // compiler-emitted vmcnt(0) drains the prefetch; one barrier/step
    cur ^= 1;
  }
  // C/D frag map (verified m89/m91): col = lane&15, row = (lane>>4)*4 + reg

  if constexpr (EPI == 0) {
    __shared__ float rsum[64][4];
#pragma unroll
    for (int fr = 0; fr < 4; ++fr) {
      int rb = i0 + fr * 16 + g * 4;
      float sr[4] = {0.f, 0.f, 0.f, 0.f};
#pragma unroll
      for (int fc = 0; fc < 4; ++fc) {
        int j = n0 + w * 64 + fc * 16 + l4;
#pragma unroll
        for (int reg = 0; reg < 4; ++reg) {
          int i = rb + reg;
          float v = fabsf(acc[fr][fc][reg]);
          if (i < N_ && j < N_) outF[((size_t)b * N_ + i) * N_ + j] = v;
          if (i < N_ && j < 288) outB[((size_t)b * N_ + i) * 288 + j] = f2bf(j < N_ ? v : 0.f);
          if (j < N_) sr[reg] += v;
        }
      }
#pragma unroll
      for (int reg = 0; reg < 4; ++reg) {
        float s = sr[reg];
        s += __shfl_xor(s, 1); s += __shfl_xor(s, 2);
        s += __shfl_xor(s, 4); s += __shfl_xor(s, 8);
        if (l4 == 0) rsum[fr * 16 + g * 4 + reg][w] = s;
      }
    }
    __syncthreads();
    if (tid < 64) {
      int i = i0 + tid;
      if (i < N_)
        atomicAdd(&dsum[(size_t)b * N_ + i],
                  rsum[tid][0] + rsum[tid][1] + rsum[tid][2] + rsum[tid][3]);
    }
  }

  if constexpr (EPI == 1) {
#pragma unroll
    for (int fr = 0; fr < 4; ++fr) {
      int rb = i0 + fr * 16 + g * 4;
      if (rb < 288) {
        float dv[4];
#pragma unroll
        for (int reg = 0; reg < 4; ++reg) {
          int j = rb + reg;
          dv[reg] = (j < N_) ? (1.f / sqrtf(1.f + dsum[(size_t)b * N_ + j])) : 0.f;  // pad rows exact 0
        }
#pragma unroll
        for (int fc = 0; fc < 4; ++fc) {
          int col = w * 64 + fc * 16 + l4;
          ushort4v pk;
#pragma unroll
          for (int reg = 0; reg < 4; ++reg)
            pk[reg] = f2bf(dv[reg] * acc[fr][fc][reg]);
          *(ushort4v*)(outB + ((size_t)b * H_ + col) * 288 + rb) = pk;
        }
      }
    }
  }

  if constexpr (EPI >= 2) {
    __shared__ float rs[64][4];
    float ratio[4][4];
    // X = dinv_i * (acc + YT[col][i]) + bias[col]   (diag of L folded via YT)
#pragma unroll
    for (int fr = 0; fr < 4; ++fr) {
      int rb = i0 + fr * 16 + g * 4;
      int rbc = min(rb, 284);                // clamped dy read (clamped rows discarded)
      float din[4];
#pragma unroll
      for (int reg = 0; reg < 4; ++reg) {
        int ic = min(rb + reg, N_ - 1);
        din[reg] = 1.f / sqrtf(1.f + dsum[(size_t)b * N_ + ic]);
      }
#pragma unroll
      for (int fc = 0; fc < 4; ++fc) {
        int col = w * 64 + fc * 16 + l4;
        ushort4v dy = *(const ushort4v*)(Bb + (size_t)col * ldb + rbc);
        float bias_v = bias[col];
#pragma unroll
        for (int reg = 0; reg < 4; ++reg) {
          float x = din[reg] * (acc[fr][fc][reg] + bf2f(dy[reg])) + bias_v;
          acc[fr][fc][reg] = x;
        }
      }
    }
    // per-row sum of x^2: in-lane over fc, shfl over 16-lane col group, LDS over waves
#pragma unroll
    for (int fr = 0; fr < 4; ++fr) {
#pragma unroll
      for (int reg = 0; reg < 4; ++reg) {
        float s = 0.f;
#pragma unroll
        for (int fc = 0; fc < 4; ++fc) { float x = acc[fr][fc][reg]; s += x * x; }
        s += __shfl_xor(s, 1); s += __shfl_xor(s, 2);
        s += __shfl_xor(s, 4); s += __shfl_xor(s, 8);
        if (l4 == 0) rs[fr * 16 + g * 4 + reg][w] = s;
      }
    }
    __syncthreads();
#pragma unroll
    for (int fr = 0; fr < 4; ++fr)
#pragma unroll
      for (int reg = 0; reg < 4; ++reg) {
        int r = fr * 16 + g * 4 + reg;
        float tot = rs[r][0] + rs[r][1] + rs[r][2] + rs[r][3];
        float norm = fmaxf(sqrtf(tot), 1e-15f);
        float scale = (norm > MAXNORM_) ? (MAXNORM_ / norm) : 1.0f;
        float pn = fmaxf(fminf(norm, MAXNORM_), 1e-15f);
        ratio[fr][reg] = atanhf(pn) / pn * scale;
      }
#pragma unroll
    for (int fr = 0; fr < 4; ++fr) {
      int rb = i0 + fr * 16 + g * 4;
#pragma unroll
      for (int fc = 0; fc < 4; ++fc) {
        int col = w * 64 + fc * 16 + l4;
#pragma unroll
        for (int reg = 0; reg < 4; ++reg) {
          int row = rb + reg;
          if (row < N_) {
            float y = ratio[fr][reg] * acc[fr][fc][reg];
            float o = fmaxf(y, 0.f) + 0.5f * __cosf(y + PHI_);
            if constexpr (EPI == 2) outB[((size_t)b * N_ + row) * H_ + col] = f2bf(o);
            else                    outF[((size_t)b * N_ + row) * H_ + col] = o;
          }
        }
      }
    }
  }
}

// ---------------------------------------------------------------------------
extern "C" void kernel_launch(void* const* d_in, const int* in_sizes, int n_in,
                              void* d_out, int out_size, void* d_ws, size_t ws_size,
                              hipStream_t stream) {
  const float* data = (const float*)d_in[0];
  const float* W1   = (const float*)d_in[1];
  const float* b1   = (const float*)d_in[2];
  const float* W2   = (const float*)d_in[3];
  const float* b2   = (const float*)d_in[4];

  float* g2   = (float*)d_out;                          // [B,N,H] f32
  float* adjF = g2 + (size_t)B_ * N_ * H_;              // [B,N,N] f32

  float* ws_f = (float*)d_ws;
  float* dsum = ws_f;                                   // BN row-sums (atomic)
  float* mean = ws_f + BN_;                             // BN
  float* rd   = ws_f + 2 * BN_;                         // BN
  unsigned short* region1 = (unsigned short*)(ws_f + 3 * BN_);
  unsigned short* z    = region1;                       // [BN][256], dead after corr
  unsigned short* YT   = region1;                       // [B*256][288], reused layer2
  unsigned short* W1T  = region1 + (size_t)B_ * H_ * 288;   // [256][288]
  unsigned short* W2T  = W1T + (size_t)H_ * 288;            // [256][256]
  unsigned short* adjB = W2T + (size_t)H_ * H_;             // [B][264][288]
  unsigned short* g1bf = (unsigned short*)d_out;        // scratch inside g2 region

  hipMemsetAsync(dsum, 0, BN_ * sizeof(float), stream);
  stats2_kernel<<<B_, 512, 0, stream>>>(data, mean, rd);
  ztile_kernel<<<dim3(5, B_), 256, 0, stream>>>(data, mean, rd, z);
  wtrans_kernel<<<dim3(5, 4), 256, 0, stream>>>(W1, W1T, N_, 288);
  wtrans_kernel<<<dim3(4, 4), 256, 0, stream>>>(W2, W2T, H_, 256);
  // adj = |z z^T| (+ bf16 copy, k-padded; + dinv row-sum partials)
  mfma_gemm_kernel<0><<<dim3(2, 5, B_), 256, 0, stream>>>(
      z, 256, (long)N_ * 256, N_, z, 256, (long)N_ * 256, N_, 8,
      adjF, adjB, dsum, nullptr);
  // Y1T[h][j] = rsqrt(1+dsum_j) * (adj @ W1)[j][h]
  mfma_gemm_kernel<1><<<dim3(1, 5, B_), 256, 0, stream>>>(
      adjB, 288, (long)N_ * 288, N_, W1T, 288, 0L, 256, 9,
      nullptr, YT, dsum, nullptr);
  // g1 = act(fkernel(dinv_i*(adj @ Y1T^T + diag) + b1))
  mfma_gemm_kernel<2><<<dim3(1, 5, B_), 256, 0, stream>>>(
      adjB, 288, (long)N_ * 288, N_, YT, 288, (long)H_ * 288, 256, 9,
      nullptr, g1bf, dsum, b1);
  // Y2T[h][j] = rsqrt(1+dsum_j) * (g1 @ W2)[j][h]
  mfma_gemm_kernel<1><<<dim3(1, 5, B_), 256, 0, stream>>>(
      g1bf, 256, (long)N_ * 256, N_, W2T, 256, 0L, 256, 8,
      nullptr, YT, dsum, nullptr);
  // g2 = act(fkernel(...)) -> final f32 output
  mfma_gemm_kernel<3><<<dim3(1, 5, B_), 256, 0, stream>>>(
      adjB, 288, (long)N_ * 288, N_, YT, 288, (long)H_ * 288, 256, 9,
      g2, nullptr, dsum, b2);
}